// Round 4
// baseline (535.233 us; speedup 1.0000x reference)
//
#include <hip/hip_runtime.h>
#include <hip/hip_bf16.h>

// B=128, N=128, L=128 -> BN=16384 rows, T=127 steps, HID=CD=128, HEADS=4.
// v4: v3's column-split GRU (audited) + GAT without the 64KB static-LDS staging
// (static __shared__ >64KB is a launch hazard; xh[b] is L2-resident anyway).
//
// GRU: 512 blocks x 256 thr (4 waves), block owns 32 rows, wave wv owns cols
// [32wv,32wv+32). whh B-frags register-resident, prescaled by log2e (r,z) /
// 2*log2e (n) so each gate nonlinearity is exp2f + rcp. h double-buffered in
// LDS fp16 with XOR swizzle (col ^ ((row&7)<<3)), ONE barrier per step,
// 2 blocks/CU so barriers overlap.
// GAT: only node i=0 is needed and adj==ones -> per-head softmax over j with
// logits xh[j].wse[h] + xh[0].wde[h]; out = 0.25*sum_h (sum_j alpha xh[j]) W[h]^T + bias.

#define BN_TOT 16384
#define TSTEPS 127
#define LOG2E  1.44269504f

typedef _Float16 f16x8 __attribute__((ext_vector_type(8)));
typedef float    f32x4 __attribute__((ext_vector_type(4)));

// ---------------------------------------------------------------------------
// Kernel 1: ws_eff[h][f] = sum_c att[h][c] * W[h][c][f]
// ---------------------------------------------------------------------------
__global__ __launch_bounds__(512) void weff_kernel(
    const float* __restrict__ gat_w, const float* __restrict__ att_src,
    const float* __restrict__ att_dst, float* __restrict__ wse, float* __restrict__ wde)
{
    int tid = threadIdx.x;              // h = tid>>7, f = tid&127
    int h = tid >> 7, f = tid & 127;
    float ss = 0.f, dd = 0.f;
    for (int c = 0; c < 128; ++c) {
        float w = gat_w[(h * 128 + c) * 128 + f];
        ss = fmaf(att_src[h * 128 + c], w, ss);
        dd = fmaf(att_dst[h * 128 + c], w, dd);
    }
    wse[tid] = ss;
    wde[tid] = dd;
}

// ---------------------------------------------------------------------------
// Kernel 2: fused features + GRU.
// MFMA 16x16x32 f16 layout: A lane l -> row=l&15, k=(l>>4)*8+j ;
// B lane l -> col=l&15, k=(l>>4)*8+j ; C lane l reg i -> row=(l>>4)*4+i, col=l&15.
// gh[row][gate] = sum_k h[row][k]*whh[gate][k]  (A=h, B=whh row-as-col).
// ---------------------------------------------------------------------------
__global__ __launch_bounds__(256, 2) void gru_kernel(
    const float* __restrict__ x,     // [BN][128][2]
    const float* __restrict__ wih,   // [384][2]
    const float* __restrict__ whh,   // [384][128]
    const float* __restrict__ bih,   // [384]
    const float* __restrict__ bhh,   // [384]
    float* __restrict__ xh)          // [BN][128]
{
    __shared__ __align__(16) _Float16 h_l[2][32 * 128];  // 16 KB double-buffered
    __shared__ __align__(16) float    fstrip[4][64];     // per-wave {v,ang} strip

    const int tid  = threadIdx.x;
    const int wv   = tid >> 6;          // wave 0..3 -> cols [32wv, 32wv+32)
    const int lane = tid & 63;
    const int c0   = lane & 15;
    const int rg   = lane >> 4;
    const int rbase = blockIdx.x * 32;

    // ---- whh B-frags -> registers, prescaled ----
    f16x8 wr[2][4], wz[2][4], wn[2][4];
    float w0r[2], w1r[2], bbr[2], w0z[2], w1z[2], bbz[2];
    float w0n[2], w1n[2], bin_[2], bhn_[2];
    #pragma unroll
    for (int ct = 0; ct < 2; ++ct) {
        const int gr = wv * 32 + ct * 16 + c0;   // r gate row of whh
        const int gz = gr + 128;                 // z
        const int gn = gr + 256;                 // n
        #pragma unroll
        for (int kt = 0; kt < 4; ++kt) {
            int ko = kt * 32 + rg * 8;
            f32x4 r0 = *(const f32x4*)&whh[gr * 128 + ko];
            f32x4 r1 = *(const f32x4*)&whh[gr * 128 + ko + 4];
            f32x4 z0 = *(const f32x4*)&whh[gz * 128 + ko];
            f32x4 z1 = *(const f32x4*)&whh[gz * 128 + ko + 4];
            f32x4 n0 = *(const f32x4*)&whh[gn * 128 + ko];
            f32x4 n1 = *(const f32x4*)&whh[gn * 128 + ko + 4];
            f16x8 fr, fz, fn;
            #pragma unroll
            for (int j = 0; j < 4; ++j) {
                fr[j]     = (_Float16)(r0[j] * LOG2E);
                fr[j + 4] = (_Float16)(r1[j] * LOG2E);
                fz[j]     = (_Float16)(z0[j] * LOG2E);
                fz[j + 4] = (_Float16)(z1[j] * LOG2E);
                fn[j]     = (_Float16)(n0[j] * (2.f * LOG2E));
                fn[j + 4] = (_Float16)(n1[j] * (2.f * LOG2E));
            }
            wr[ct][kt] = fr; wz[ct][kt] = fz; wn[ct][kt] = fn;
        }
        w0r[ct] = wih[gr * 2] * LOG2E;        w1r[ct] = wih[gr * 2 + 1] * LOG2E;
        w0z[ct] = wih[gz * 2] * LOG2E;        w1z[ct] = wih[gz * 2 + 1] * LOG2E;
        w0n[ct] = wih[gn * 2] * 2.f * LOG2E;  w1n[ct] = wih[gn * 2 + 1] * 2.f * LOG2E;
        bbr[ct] = (bih[gr] + bhh[gr]) * LOG2E;
        bbz[ct] = (bih[gz] + bhh[gz]) * LOG2E;
        bin_[ct] = bih[gn] * 2.f * LOG2E;     // stays outside r*( )
        bhn_[ct] = bhh[gn] * 2.f * LOG2E;     // inside r*( ) -> MFMA acc init
    }

    // ---- zero h buffer 0 (h0 = 0): 32*128 halves = 2048 ints ----
    {
        int* hz = (int*)h_l[0];
        #pragma unroll
        for (int i = 0; i < 8; ++i) hz[i * 256 + tid] = 0;
    }
    __syncthreads();

    // ---- x prologue: lane&31 <-> row (rbase + lane&31); lanes 32-63 duplicate ----
    const float2* xp = (const float2*)x;
    const int r0i = rbase + (lane & 31);
    float2 xc = xp[r0i * 128 + 0];
    float2 xn = xp[r0i * 128 + 1];
    float vprev = 0.f;

    float h_reg[2][2][4];   // [rt][ct][i]; row=rt*16+rg*4+i, col=wv*32+ct*16+c0
    #pragma unroll
    for (int rt = 0; rt < 2; ++rt)
        #pragma unroll
        for (int ct = 0; ct < 2; ++ct)
            #pragma unroll
            for (int i = 0; i < 4; ++i) h_reg[rt][ct][i] = 0.f;

    const int swz_a = (c0 & 7) << 3;

    #pragma unroll 1
    for (int t = 0; t < TSTEPS; ++t) {
        // ---- features for row r0i (lanes 32-63 write identical values: benign) ----
        {
            float dx = xn.x - xc.x, dy = xn.y - xc.y;
            float v  = sqrtf(dx * dx + dy * dy);
            float pv = (t == 0) ? v : vprev;
            float cs = (pv * v) / ((pv + 1e-6f) * (v + 1e-6f));
            cs = fminf(1.f, fmaxf(-1.f, cs));
            float an = acosf(cs);
            vprev = v; xc = xn;
            if (t < TSTEPS - 1) xn = xp[r0i * 128 + t + 2];
            *(float2*)&fstrip[wv][(lane & 31) * 2] = make_float2(v, an);
        }

        const _Float16* hb = h_l[t & 1];
        _Float16*       hw = h_l[(t & 1) ^ 1];

        #pragma unroll
        for (int rt = 0; rt < 2; ++rt) {
            // features of the 4 rows (base = rt*16+rg*4) this lane's C-frags cover
            f32x4 f0 = *(const f32x4*)&fstrip[wv][(rt * 16 + rg * 4) * 2];
            f32x4 f1 = *(const f32x4*)&fstrip[wv][(rt * 16 + rg * 4) * 2 + 4];
            float vv[4] = {f0[0], f0[2], f1[0], f1[2]};
            float aa[4] = {f0[1], f0[3], f1[1], f1[3]};

            // A-frags: h_prev[rt*16+c0][k], swizzle keyed by row&7 = c0&7
            f16x8 afr[4];
            #pragma unroll
            for (int kt = 0; kt < 4; ++kt) {
                int ko = kt * 32 + rg * 8;
                afr[kt] = *(const f16x8*)&hb[(rt * 16 + c0) * 128 + (ko ^ swz_a)];
            }

            #pragma unroll
            for (int ct = 0; ct < 2; ++ct) {
                // acc init = input-gate part + folded biases (prescaled)
                f32x4 ar, az, an_;
                float gxn[4];
                #pragma unroll
                for (int i = 0; i < 4; ++i) {
                    ar[i]  = fmaf(vv[i], w0r[ct], fmaf(aa[i], w1r[ct], bbr[ct]));
                    az[i]  = fmaf(vv[i], w0z[ct], fmaf(aa[i], w1z[ct], bbz[ct]));
                    an_[i] = bhn_[ct];
                    gxn[i] = fmaf(vv[i], w0n[ct], fmaf(aa[i], w1n[ct], bin_[ct]));
                }
                #pragma unroll
                for (int kt = 0; kt < 4; ++kt) {
                    ar  = __builtin_amdgcn_mfma_f32_16x16x32_f16(afr[kt], wr[ct][kt], ar,  0, 0, 0);
                    az  = __builtin_amdgcn_mfma_f32_16x16x32_f16(afr[kt], wz[ct][kt], az,  0, 0, 0);
                    an_ = __builtin_amdgcn_mfma_f32_16x16x32_f16(afr[kt], wn[ct][kt], an_, 0, 0, 0);
                }
                // r = sigma, z = sigma, nn = tanh(.)  -- args prescaled for exp2
                #pragma unroll
                for (int i = 0; i < 4; ++i) {
                    float r  = __builtin_amdgcn_rcpf(1.f + exp2f(-ar[i]));
                    float z  = __builtin_amdgcn_rcpf(1.f + exp2f(-az[i]));
                    float sn = fmaf(r, an_[i], gxn[i]);
                    float nn = fmaf(-2.f, __builtin_amdgcn_rcpf(1.f + exp2f(sn)), 1.f);
                    float hv = h_reg[rt][ct][i];
                    hv = nn + z * (hv - nn);            // (1-z)*nn + z*h
                    h_reg[rt][ct][i] = hv;
                    int row = rt * 16 + rg * 4 + i;
                    int col = wv * 32 + ct * 16 + c0;
                    hw[row * 128 + (col ^ ((row & 7) << 3))] = (_Float16)hv;
                }
            }
        }
        __syncthreads();
    }

    // ---- store final h (fp32 register chain) ----
    #pragma unroll
    for (int rt = 0; rt < 2; ++rt)
        #pragma unroll
        for (int ct = 0; ct < 2; ++ct)
            #pragma unroll
            for (int i = 0; i < 4; ++i) {
                int r = rbase + rt * 16 + rg * 4 + i;
                xh[r * 128 + wv * 32 + ct * 16 + c0] = h_reg[rt][ct][i];
            }
}

// ---------------------------------------------------------------------------
// Kernel 3: collapsed DenseGATConv for node i=0. One block per batch b.
// No big LDS staging: xh[b] (64KB) is L2-resident; both passes read it coalesced.
// ---------------------------------------------------------------------------
__global__ __launch_bounds__(256) void gat_kernel(
    const float* __restrict__ xh,     // [B*N][128]
    const float* __restrict__ gat_w,  // [512][128]
    const float* __restrict__ gbias,  // [128]
    const float* __restrict__ wse,    // [4][128]
    const float* __restrict__ wde,    // [4][128]
    float* __restrict__ out)          // [B][128]
{
    __shared__ float asrc[512];                   // [j][h]
    __shared__ float wgt[512];                    // [j][h]
    __shared__ __align__(16) float m_l[512];      // [h][f]
    __shared__ float asd[4];

    const int b = blockIdx.x, tid = threadIdx.x;
    const float* xb = xh + b * 16384;

    // a_src[j][h] = xh[j] . wse[h]   (4 lanes share each xh 16B read -> L1 broadcast)
    #pragma unroll
    for (int p2 = 0; p2 < 2; ++p2) {
        int p = p2 * 256 + tid;
        int j = p >> 2, h = p & 3;
        const float* wrp = wse + h * 128;
        const float* xr  = xb + j * 128;
        float acc = 0.f;
        for (int f = 0; f < 128; f += 4) {
            f32x4 xv  = *(const f32x4*)&xr[f];
            f32x4 wvv = *(const f32x4*)&wrp[f];
            acc += xv[0] * wvv[0] + xv[1] * wvv[1] + xv[2] * wvv[2] + xv[3] * wvv[3];
        }
        asrc[j * 4 + h] = acc;
    }
    if (tid < 4) {     // a_dst at node 0
        const float* wrp = wde + tid * 128;
        float acc = 0.f;
        for (int f = 0; f < 128; f += 4) {
            f32x4 xv  = *(const f32x4*)&xb[f];
            f32x4 wvv = *(const f32x4*)&wrp[f];
            acc += xv[0] * wvv[0] + xv[1] * wvv[1] + xv[2] * wvv[2] + xv[3] * wvv[3];
        }
        asd[tid] = acc;
    }
    __syncthreads();

    // per-head softmax over j (wave h handles head h; lanes hold j and j+64)
    {
        int h = tid >> 6, j = tid & 63;
        float a0 = asrc[j * 4 + h] + asd[h];
        float a1 = asrc[(j + 64) * 4 + h] + asd[h];
        float e0 = a0 > 0.f ? a0 : 0.2f * a0;     // leaky_relu 0.2
        float e1 = a1 > 0.f ? a1 : 0.2f * a1;
        float mx = fmaxf(e0, e1);
        #pragma unroll
        for (int m = 32; m >= 1; m >>= 1) mx = fmaxf(mx, __shfl_xor(mx, m, 64));
        float p0 = __expf(e0 - mx), p1 = __expf(e1 - mx);
        float s = p0 + p1;
        #pragma unroll
        for (int m = 32; m >= 1; m >>= 1) s += __shfl_xor(s, m, 64);
        float inv = 1.f / s;
        wgt[j * 4 + h] = p0 * inv;
        wgt[(j + 64) * 4 + h] = p1 * inv;
    }
    __syncthreads();

    // m[h][f] = sum_j wgt[j][h] * xh[j][f]   (lane f consecutive -> coalesced 256B)
    #pragma unroll
    for (int p2 = 0; p2 < 2; ++p2) {
        int p = p2 * 256 + tid;
        int h = p >> 7, f = p & 127;
        float acc = 0.f;
        for (int j = 0; j < 128; ++j)
            acc = fmaf(wgt[j * 4 + h], xb[j * 128 + f], acc);
        m_l[h * 128 + f] = acc;
    }
    __syncthreads();

    // out[b][c] = 0.25 * sum_h sum_f m[h][f] * W[h][c][f] + bias[c]
    if (tid < 128) {
        int c = tid;
        float acc = 0.f;
        #pragma unroll
        for (int h = 0; h < 4; ++h) {
            const float* wrp = gat_w + (h * 128 + c) * 128;
            const float* mr  = m_l + h * 128;
            for (int f = 0; f < 128; f += 4) {
                f32x4 wvv = *(const f32x4*)&wrp[f];
                f32x4 mv  = *(const f32x4*)&mr[f];
                acc += wvv[0] * mv[0] + wvv[1] * mv[1] + wvv[2] * mv[2] + wvv[3] * mv[3];
            }
        }
        out[b * 128 + c] = 0.25f * acc + gbias[c];
    }
}

// ---------------------------------------------------------------------------
extern "C" void kernel_launch(void* const* d_in, const int* in_sizes, int n_in,
                              void* d_out, int out_size, void* d_ws, size_t ws_size,
                              hipStream_t stream) {
    const float* x       = (const float*)d_in[0];
    const float* wih     = (const float*)d_in[1];
    const float* whh     = (const float*)d_in[2];
    const float* bih     = (const float*)d_in[3];
    const float* bhh     = (const float*)d_in[4];
    const float* gat_w   = (const float*)d_in[5];
    const float* att_src = (const float*)d_in[6];
    const float* att_dst = (const float*)d_in[7];
    const float* gbias   = (const float*)d_in[8];
    float* outp = (float*)d_out;

    float* ws  = (float*)d_ws;
    float* xh  = ws;                       // 16384*128 f32 (8.39 MB)
    float* wse = ws + BN_TOT * 128;        // 512
    float* wde = wse + 512;                // 512

    weff_kernel<<<1, 512, 0, stream>>>(gat_w, att_src, att_dst, wse, wde);
    gru_kernel<<<512, 256, 0, stream>>>(x, wih, whh, bih, bhh, xh);
    gat_kernel<<<128, 256, 0, stream>>>(xh, gat_w, gbias, wse, wde, outp);
}